// Round 6
// baseline (348.953 us; speedup 1.0000x reference)
//
#include <hip/hip_runtime.h>
#include <hip/hip_fp16.h>

typedef int   v4i __attribute__((ext_vector_type(4)));
typedef unsigned int v4u __attribute__((ext_vector_type(4)));

constexpr int TPW        = 4;     // tokens per wave
constexpr int NTOK_BLK   = 32;    // tokens per block (8 waves * TPW)
constexpr int SLICE_ROWS = 4096;  // rows per pass = 64 KB fp16 slice
constexpr int NPASS      = 16;    // passes per codebook (65536 / 4096)
constexpr int NPASS_ALL  = 32;    // both codebooks

// ---------- pre-pass: f32 codebooks -> fp16 (lossless, data was fp16) ------
__global__ __launch_bounds__(256) void cvt_kernel(
    const float* __restrict__ cb1, const float* __restrict__ cb2,
    unsigned int* __restrict__ o1, unsigned int* __restrict__ o2)
{
    const int r = blockIdx.x * 256 + threadIdx.x;        // 0..131071
    const float* src = (r < 65536) ? (cb1 + (size_t)r * 8)
                                   : (cb2 + (size_t)(r - 65536) * 8);
    unsigned int* dst = (r < 65536) ? (o1 + (size_t)r * 4)
                                    : (o2 + (size_t)(r - 65536) * 4);
    const float4 a = ((const float4*)src)[0];
    const float4 b = ((const float4*)src)[1];
    __half2 h0 = __floats2half2_rn(a.x, a.y);
    __half2 h1 = __floats2half2_rn(a.z, a.w);
    __half2 h2 = __floats2half2_rn(b.x, b.y);
    __half2 h3 = __floats2half2_rn(b.z, b.w);
    v4u o;
    o.x = *(unsigned int*)&h0; o.y = *(unsigned int*)&h1;
    o.z = *(unsigned int*)&h2; o.w = *(unsigned int*)&h3;
    *(v4u*)dst = o;
}

// ---------- helpers --------------------------------------------------------
// Async 16 B global->LDS DMA. LDS dest is wave-uniform base; HW scatters
// lane i to base + i*16. Global src is per-lane. Counted by vmcnt.
__device__ __forceinline__ void gload_lds16(const unsigned int* g, unsigned int* l)
{
    __builtin_amdgcn_global_load_lds(
        (const __attribute__((address_space(1))) unsigned int*)g,
        (__attribute__((address_space(3))) unsigned int*)l, 16, 0, 0);
}

// fp16 pairs -> f32, combined with residual scale.
__device__ __forceinline__ void convert8(const v4u g1[4], const v4u g2[4],
    const float ws, const float ws2, float v[32])
{
    #pragma unroll
    for (int c = 0; c < 4; ++c) {
        const unsigned int au[4] = { g1[c].x, g1[c].y, g1[c].z, g1[c].w };
        const unsigned int bu[4] = { g2[c].x, g2[c].y, g2[c].z, g2[c].w };
        #pragma unroll
        for (int p = 0; p < 4; ++p) {
            const float2 fa = __half22float2(*(const __half2*)&au[p]);
            const float2 fb = __half22float2(*(const __half2*)&bu[p]);
            v[8*c + 2*p]     = fa.x * ws + fb.x * ws2;
            v[8*c + 2*p + 1] = fa.y * ws + fb.y * ws2;
        }
    }
}

// FHT(2048) + SV + store for one token. v[] holds combined/scaled inputs on
// entry (element e = lane*32 + r). L is this wave's private 8 KB LDS region.
__device__ __forceinline__ void process_tok(float v[32], float* __restrict__ L,
    const int lane, const float* __restrict__ SV, float* __restrict__ outp)
{
    // FHT bits 0..4 (within-thread)
    #pragma unroll
    for (int h = 1; h < 32; h <<= 1) {
        #pragma unroll
        for (int r = 0; r < 32; ++r) {
            if ((r & h) == 0) { float a = v[r], b = v[r + h]; v[r] = a + b; v[r + h] = a - b; }
        }
    }

    // Transposed LDS write (wave-private region, wave-synchronous).
    // col' = ((t>>2) ^ (j&15))*4 + (t&3): 2 lanes/bank, free.
    __builtin_amdgcn_wave_barrier();           // prior reads of L complete first
    {
        const int t4 = lane >> 2, tl = lane & 3;
        #pragma unroll
        for (int j = 0; j < 32; ++j) {
            const int col = (((t4 ^ (j & 15)) << 2) | tl);
            L[(j << 6) + col] = v[j];
        }
    }
    __builtin_amdgcn_wave_barrier();           // pin ordering; lgkmcnt inserted by compiler

    // Phase 2: lane u = 2*j0 + b reads row j0, cols t = 32b..32b+31.
    const int j0 = lane >> 1;
    const int b  = lane & 1;
    float w[32];
    {
        const float4* Lr = (const float4*)(L + (j0 << 6));
        #pragma unroll
        for (int c = 0; c < 8; ++c) {
            const int ch = ((b << 3) + c) ^ (j0 & 15);
            const float4 f = Lr[ch];
            w[4*c + 0] = f.x; w[4*c + 1] = f.y; w[4*c + 2] = f.z; w[4*c + 3] = f.w;
        }
    }
    __builtin_amdgcn_wave_barrier();

    // SV prefetch (8 KB table, cache-hot): latency hides under phase-2 FHT.
    const int ebase = (b << 10) | j0;
    float svv[32];
    #pragma unroll
    for (int r = 0; r < 32; ++r) svv[r] = SV[ebase + (r << 5)];

    // FHT bits 5..9 (within-thread)
    #pragma unroll
    for (int h = 1; h < 32; h <<= 1) {
        #pragma unroll
        for (int r = 0; r < 32; ++r) {
            if ((r & h) == 0) { float a = w[r], bb = w[r + h]; w[r] = a + bb; w[r + h] = a - bb; }
        }
    }

    // FHT bit 10: partner lane u^1
    #pragma unroll
    for (int r = 0; r < 32; ++r) {
        const float o = __shfl_xor(w[r], 1, 64);
        w[r] = b ? (o - w[r]) : (w[r] + o);
    }

    // non-temporal f32 store: e = 1024*b + 32*r + j0 (coalesced per instr)
    #pragma unroll
    for (int r = 0; r < 32; ++r) {
        const int e = ebase + (r << 5);
        __builtin_nontemporal_store(w[r] * svv[r], &outp[e]);
    }
}

// ---------- main kernel: double-buffered LDS codebook slices ---------------
// 512 threads = 8 waves, 32 tokens/block (4/wave), grid = 512 blocks.
// Both codebooks stream through a 2x64 KB LDS double-buffer in 32 passes via
// global_load_lds (async DMA, vmcnt-counted); counted vmcnt keeps next-pass
// DMAs in flight across raw s_barriers. Random gathers are exec-masked
// ds_read_b128 from the resident slice, off the TCP miss path.
// amdgpu_waves_per_eu(2,2): pin 2 waves/EU -> 256-VGPR budget so the 128
// gathered registers live in arch VGPRs (ds_read writes the dest directly;
// one coalesced lgkmcnt wait per pass). At 128 VGPRs the compiler banked
// them in AGPRs, forcing a serialized lgkmcnt(0)+v_accvgpr_write per
// masked read (~120 cyc each) — round-5's hidden cost.
__global__ void __launch_bounds__(512)
__attribute__((amdgpu_waves_per_eu(2, 2)))
e8rht_kernel_h(
    const int* __restrict__ input_ids,
    const int* __restrict__ Qidxs,
    const int* __restrict__ Qidxs2,
    const unsigned int* __restrict__ cb1h,   // fp16 pairs: row = 4 uints (16 B)
    const unsigned int* __restrict__ cb2h,
    const float* __restrict__ SV,
    const float* __restrict__ Wscale,
    const float* __restrict__ inv_resid,
    float* __restrict__ out)
{
    __shared__ __align__(16) unsigned int slice[2][SLICE_ROWS * 4];  // 128 KB
    const int wave = threadIdx.x >> 6;
    const int lane = threadIdx.x & 63;

    const float ws  = Wscale[0];
    const float ws2 = ws * inv_resid[0];
    const int tok0 = blockIdx.x * NTOK_BLK + wave * TPW;

    // Packed index: pk = idx*16 = (pass << 16) | byte_offset_within_slice.
    // One shift at setup; per-pass test = (pk>>16)==p, addr = pk & 0xFFFF.
    unsigned int pk1[TPW * 4], pk2[TPW * 4];
    #pragma unroll
    for (int t = 0; t < TPW; ++t) {
        const int tid = input_ids[tok0 + t];
        const v4i a = __builtin_nontemporal_load((const v4i*)(Qidxs  + (size_t)tid * 256 + lane * 4));
        const v4i b = __builtin_nontemporal_load((const v4i*)(Qidxs2 + (size_t)tid * 256 + lane * 4));
        pk1[t*4+0] = (unsigned int)(a.x & 0xFFFF) << 4;
        pk1[t*4+1] = (unsigned int)(a.y & 0xFFFF) << 4;
        pk1[t*4+2] = (unsigned int)(a.z & 0xFFFF) << 4;
        pk1[t*4+3] = (unsigned int)(a.w & 0xFFFF) << 4;
        pk2[t*4+0] = (unsigned int)(b.x & 0xFFFF) << 4;
        pk2[t*4+1] = (unsigned int)(b.y & 0xFFFF) << 4;
        pk2[t*4+2] = (unsigned int)(b.z & 0xFFFF) << 4;
        pk2[t*4+3] = (unsigned int)(b.w & 0xFFFF) << 4;
    }

    v4u G1[TPW * 4], G2[TPW * 4];   // each written exactly once across passes

    // Staging layout: wave w owns uints [w*2048, (w+1)*2048) of each slice
    // (8 KB); 8 x 1 KB DMA chunks; lane l covers l*4 within each chunk.
    const int soff = wave * 2048 + lane * 4;   // per-lane global offset (uints)

    // prologue: pass 0 -> buf 0
    {
        const unsigned int* s = cb1h + soff;
        unsigned int* d = &slice[0][wave * 2048];   // wave-uniform LDS dest
        #pragma unroll
        for (int k = 0; k < 8; ++k) gload_lds16(s + k * 256, d + k * 256);
    }

    #pragma unroll 1
    for (int p = 0; p < NPASS_ALL; ++p) {
        const char* buf = (const char*)&slice[p & 1][0];
        if (p < NPASS_ALL - 1) {
            // Issue pass p+1 into the other buffer (its readers finished at
            // the trailing barrier of iteration p-1). These 8 DMAs stay in
            // flight across the barrier below.
            const int pn = p + 1;
            const unsigned int* s = (pn < NPASS
                ? cb1h + (size_t)pn * (SLICE_ROWS * 4)
                : cb2h + (size_t)(pn - NPASS) * (SLICE_ROWS * 4)) + soff;
            unsigned int* d = &slice[pn & 1][wave * 2048];
            #pragma unroll
            for (int k = 0; k < 8; ++k) gload_lds16(s + k * 256, d + k * 256);
            asm volatile("s_waitcnt vmcnt(8)" ::: "memory");  // pass p done, p+1 flying
        } else {
            asm volatile("s_waitcnt vmcnt(0)" ::: "memory");
        }
        __builtin_amdgcn_sched_barrier(0);
        __builtin_amdgcn_s_barrier();            // all waves' pass-p regions written
        __builtin_amdgcn_sched_barrier(0);

        if (p < NPASS) {
            #pragma unroll
            for (int k = 0; k < TPW * 4; ++k) {
                if ((pk1[k] >> 16) == (unsigned int)p)
                    G1[k] = *(const v4u*)(buf + (pk1[k] & 0xFFFFu));
            }
        } else {
            const unsigned int ps = (unsigned int)(p - NPASS);
            #pragma unroll
            for (int k = 0; k < TPW * 4; ++k) {
                if ((pk2[k] >> 16) == ps)
                    G2[k] = *(const v4u*)(buf + (pk2[k] & 0xFFFFu));
            }
        }
        // Drain own ds_reads before signalling "done reading" (cross-wave
        // hazard vs next pass's DMA into this buffer).
        asm volatile("s_waitcnt lgkmcnt(0)" ::: "memory");
        __builtin_amdgcn_sched_barrier(0);
        __builtin_amdgcn_s_barrier();
        __builtin_amdgcn_sched_barrier(0);
    }

    // All gathers complete (trailing barrier); repurpose slice[0] as the
    // per-wave 8 KB transpose scratch (8 waves x 8 KB = 64 KB).
    float* L = ((float*)&slice[0][0]) + wave * 2048;
    #pragma unroll
    for (int t = 0; t < TPW; ++t) {
        float v[32];
        convert8(&G1[t * 4], &G2[t * 4], ws, ws2, v);
        process_tok(v, L, lane, SV, out + (size_t)(tok0 + t) * 2048);
    }
}

// ---------- fallback (f32 gathers, 1 token/wave) — used if ws too small ----
__global__ __launch_bounds__(256, 4) void e8rht_kernel_f(
    const int* __restrict__ input_ids,
    const int* __restrict__ Qidxs,
    const int* __restrict__ Qidxs2,
    const float* __restrict__ codebook,
    const float* __restrict__ codebook2,
    const float* __restrict__ SV,
    const float* __restrict__ Wscale,
    const float* __restrict__ inv_resid,
    float* __restrict__ out)
{
    __shared__ __align__(16) float lds[4 * 2048];
    const int wave = threadIdx.x >> 6;
    const int lane = threadIdx.x & 63;
    const int tok  = blockIdx.x * 4 + wave;

    const float ws  = Wscale[0];
    const float ws2 = ws * inv_resid[0];
    const int tid = input_ids[tok];

    const int4 q1 = *(const int4*)(Qidxs  + (size_t)tid * 256 + lane * 4);
    const int4 q2 = *(const int4*)(Qidxs2 + (size_t)tid * 256 + lane * 4);

    float v[32];
    {
        const int i1[4] = { q1.x & 0xFFFF, q1.y & 0xFFFF, q1.z & 0xFFFF, q1.w & 0xFFFF };
        const int i2[4] = { q2.x & 0xFFFF, q2.y & 0xFFFF, q2.z & 0xFFFF, q2.w & 0xFFFF };
        #pragma unroll
        for (int c = 0; c < 4; ++c) {
            const float4* r1 = (const float4*)(codebook  + (size_t)i1[c] * 8);
            const float4* r2 = (const float4*)(codebook2 + (size_t)i2[c] * 8);
            const float4 a0 = r1[0], a1 = r1[1];
            const float4 b0 = r2[0], b1 = r2[1];
            v[8*c+0]=a0.x*ws+b0.x*ws2; v[8*c+1]=a0.y*ws+b0.y*ws2;
            v[8*c+2]=a0.z*ws+b0.z*ws2; v[8*c+3]=a0.w*ws+b0.w*ws2;
            v[8*c+4]=a1.x*ws+b1.x*ws2; v[8*c+5]=a1.y*ws+b1.y*ws2;
            v[8*c+6]=a1.z*ws+b1.z*ws2; v[8*c+7]=a1.w*ws+b1.w*ws2;
        }
    }
    #pragma unroll
    for (int h = 1; h < 32; h <<= 1)
        #pragma unroll
        for (int r = 0; r < 32; ++r)
            if ((r & h) == 0) { float a=v[r],b=v[r+h]; v[r]=a+b; v[r+h]=a-b; }

    float* L = lds + wave * 2048;
    {
        const int t4 = lane >> 2, tl = lane & 3;
        #pragma unroll
        for (int j = 0; j < 32; ++j)
            L[(j << 6) + (((t4 ^ (j & 15)) << 2) | tl)] = v[j];
    }
    __syncthreads();
    const int j0 = lane >> 1;
    const int b  = lane & 1;
    float w[32];
    {
        const float4* Lr = (const float4*)(L + (j0 << 6));
        #pragma unroll
        for (int c = 0; c < 8; ++c) {
            const float4 f = Lr[((b << 3) + c) ^ (j0 & 15)];
            w[4*c+0]=f.x; w[4*c+1]=f.y; w[4*c+2]=f.z; w[4*c+3]=f.w;
        }
    }
    #pragma unroll
    for (int h = 1; h < 32; h <<= 1)
        #pragma unroll
        for (int r = 0; r < 32; ++r)
            if ((r & h) == 0) { float a=w[r],bb=w[r+h]; w[r]=a+bb; w[r+h]=a-bb; }
    #pragma unroll
    for (int r = 0; r < 32; ++r) {
        const float o = __shfl_xor(w[r], 1, 64);
        w[r] = b ? (o - w[r]) : (w[r] + o);
    }
    const size_t obase = (size_t)tok * 2048;
    const int ebase = (b << 10) | j0;
    #pragma unroll
    for (int r = 0; r < 32; ++r) {
        const int e = ebase + (r << 5);
        out[obase + e] = w[r] * SV[e];
    }
}

extern "C" void kernel_launch(void* const* d_in, const int* in_sizes, int n_in,
                              void* d_out, int out_size, void* d_ws, size_t ws_size,
                              hipStream_t stream) {
    const int* input_ids   = (const int*)d_in[0];
    const int* Qidxs       = (const int*)d_in[1];
    const int* Qidxs2      = (const int*)d_in[2];
    const float* codebook  = (const float*)d_in[3];
    const float* codebook2 = (const float*)d_in[4];
    const float* SV        = (const float*)d_in[5];
    const float* wscale    = (const float*)d_in[6];
    const float* irs       = (const float*)d_in[7];
    float* out             = (float*)d_out;

    const int n_tok = in_sizes[0];          // 16384

    const size_t cb_h_bytes = (size_t)65536 * 8 * 2;   // 1 MB per codebook
    if (ws_size >= 2 * cb_h_bytes && (n_tok % NTOK_BLK) == 0) {
        unsigned int* cb1h = (unsigned int*)d_ws;
        unsigned int* cb2h = (unsigned int*)((char*)d_ws + cb_h_bytes);
        cvt_kernel<<<512, 256, 0, stream>>>(codebook, codebook2, cb1h, cb2h);
        const int grid = n_tok / NTOK_BLK;              // 512 blocks of 512
        e8rht_kernel_h<<<grid, 512, 0, stream>>>(input_ids, Qidxs, Qidxs2,
                                                 cb1h, cb2h, SV, wscale, irs, out);
    } else {
        const int grid = n_tok / 4;                     // 4096 blocks of 256
        e8rht_kernel_f<<<grid, 256, 0, stream>>>(input_ids, Qidxs, Qidxs2,
                                                 codebook, codebook2, SV,
                                                 wscale, irs, out);
    }
}

// Round 7
// 348.834 us; speedup vs baseline: 1.0003x; 1.0003x over previous
//
#include <hip/hip_runtime.h>
#include <hip/hip_fp16.h>

constexpr int WPB = 4;   // waves (=tokens) per block

typedef int   v4i __attribute__((ext_vector_type(4)));
typedef unsigned int v4u __attribute__((ext_vector_type(4)));

// ---------- pre-pass: f32 codebooks -> fp16 (lossless, data was fp16) ------
__global__ __launch_bounds__(256) void cvt_kernel(
    const float* __restrict__ cb1, const float* __restrict__ cb2,
    unsigned int* __restrict__ o1, unsigned int* __restrict__ o2)
{
    const int r = blockIdx.x * 256 + threadIdx.x;        // 0..131071
    const float* src = (r < 65536) ? (cb1 + (size_t)r * 8)
                                   : (cb2 + (size_t)(r - 65536) * 8);
    unsigned int* dst = (r < 65536) ? (o1 + (size_t)r * 4)
                                    : (o2 + (size_t)(r - 65536) * 4);
    const float4 a = ((const float4*)src)[0];
    const float4 b = ((const float4*)src)[1];
    __half2 h0 = __floats2half2_rn(a.x, a.y);
    __half2 h1 = __floats2half2_rn(a.z, a.w);
    __half2 h2 = __floats2half2_rn(b.x, b.y);
    __half2 h3 = __floats2half2_rn(b.z, b.w);
    v4u o;
    o.x = *(unsigned int*)&h0; o.y = *(unsigned int*)&h1;
    o.z = *(unsigned int*)&h2; o.w = *(unsigned int*)&h3;
    *(v4u*)dst = o;
}

// 16 B gather that BYPASSES L1 (sc0) and streams (nt). L1 hit rate on the
// 2 MB codebooks is ~2% (32 KB L1) — line fills are pure overhead; sc0
// reads L2 directly. NOTE: asm loads are invisible to the compiler's vmcnt
// tracking — caller must s_waitcnt vmcnt(0) + sched_barrier before use.
__device__ __forceinline__ v4u gload16_sc0(const unsigned int* p) {
    v4u r;
    asm volatile("global_load_dwordx4 %0, %1, off sc0 nt"
                 : "=v"(r) : "v"(p) : "memory");
    return r;
}

// ---------- main kernel (fp16 codebook gathers, L1-bypass) -----------------
__global__ __launch_bounds__(256, 4) void e8rht_kernel_h(
    const int* __restrict__ input_ids,
    const int* __restrict__ Qidxs,
    const int* __restrict__ Qidxs2,
    const unsigned int* __restrict__ cb1h,   // fp16 pairs: row = 4 uints (16 B)
    const unsigned int* __restrict__ cb2h,
    const float* __restrict__ SV,
    const float* __restrict__ Wscale,
    const float* __restrict__ inv_resid,
    float* __restrict__ out)
{
    __shared__ __align__(16) float lds[WPB * 2048];
    const int wave = threadIdx.x >> 6;
    const int lane = threadIdx.x & 63;
    const int tok  = blockIdx.x * WPB + wave;

    const float ws  = Wscale[0];
    const float ws2 = ws * inv_resid[0];
    const int tid = input_ids[tok];

    // streaming reads: non-temporal (keep L2 for codebooks)
    const v4i q1 = __builtin_nontemporal_load((const v4i*)(Qidxs  + (size_t)tid * 256 + lane * 4));
    const v4i q2 = __builtin_nontemporal_load((const v4i*)(Qidxs2 + (size_t)tid * 256 + lane * 4));

    float v[32];
    {
        const int i1[4] = { q1.x & 0xFFFF, q1.y & 0xFFFF, q1.z & 0xFFFF, q1.w & 0xFFFF };
        const int i2[4] = { q2.x & 0xFFFF, q2.y & 0xFFFF, q2.z & 0xFFFF, q2.w & 0xFFFF };

        // All 8 gathers issued back-to-back (volatile asm preserves order),
        // then one drain. Values are unsafe to read before the waitcnt; the
        // sched_barrier stops the compiler hoisting converts above it.
        v4u a0 = gload16_sc0(cb1h + (size_t)i1[0] * 4);
        v4u a1 = gload16_sc0(cb1h + (size_t)i1[1] * 4);
        v4u a2 = gload16_sc0(cb1h + (size_t)i1[2] * 4);
        v4u a3 = gload16_sc0(cb1h + (size_t)i1[3] * 4);
        v4u b0 = gload16_sc0(cb2h + (size_t)i2[0] * 4);
        v4u b1 = gload16_sc0(cb2h + (size_t)i2[1] * 4);
        v4u b2 = gload16_sc0(cb2h + (size_t)i2[2] * 4);
        v4u b3 = gload16_sc0(cb2h + (size_t)i2[3] * 4);
        asm volatile("s_waitcnt vmcnt(0)" ::: "memory");
        __builtin_amdgcn_sched_barrier(0);

        const v4u ga[4] = { a0, a1, a2, a3 };
        const v4u gb[4] = { b0, b1, b2, b3 };
        #pragma unroll
        for (int c = 0; c < 4; ++c) {
            const unsigned int au[4] = { ga[c].x, ga[c].y, ga[c].z, ga[c].w };
            const unsigned int bu[4] = { gb[c].x, gb[c].y, gb[c].z, gb[c].w };
            #pragma unroll
            for (int p = 0; p < 4; ++p) {
                const float2 fa = __half22float2(*(const __half2*)&au[p]);
                const float2 fb = __half22float2(*(const __half2*)&bu[p]);
                v[8*c + 2*p]     = fa.x * ws + fb.x * ws2;
                v[8*c + 2*p + 1] = fa.y * ws + fb.y * ws2;
            }
        }
    }

    // FHT bits 0..4 (within-thread)
    #pragma unroll
    for (int h = 1; h < 32; h <<= 1) {
        #pragma unroll
        for (int r = 0; r < 32; ++r) {
            if ((r & h) == 0) {
                float a = v[r], b = v[r + h];
                v[r] = a + b;
                v[r + h] = a - b;
            }
        }
    }

    // Transposed LDS write (wave-private region, wave-synchronous — no block
    // barrier needed). col' = ((t>>2) ^ (j&15))*4 + (t&3): 2 lanes/bank, free.
    float* L = lds + wave * 2048;
    {
        const int t4 = lane >> 2, tl = lane & 3;
        #pragma unroll
        for (int j = 0; j < 32; ++j) {
            const int col = (((t4 ^ (j & 15)) << 2) | tl);
            L[(j << 6) + col] = v[j];
        }
    }
    __builtin_amdgcn_wave_barrier();   // pin ordering; lgkmcnt inserted by compiler

    // Phase 2: lane u = 2*j0 + b reads row j0, cols t = 32b..32b+31.
    const int j0 = lane >> 1;
    const int b  = lane & 1;
    float w[32];
    {
        const float4* Lr = (const float4*)(L + (j0 << 6));
        #pragma unroll
        for (int c = 0; c < 8; ++c) {
            const int ch = ((b << 3) + c) ^ (j0 & 15);
            const float4 f = Lr[ch];
            w[4*c + 0] = f.x; w[4*c + 1] = f.y; w[4*c + 2] = f.z; w[4*c + 3] = f.w;
        }
    }

    // FHT bits 5..9 (within-thread)
    #pragma unroll
    for (int h = 1; h < 32; h <<= 1) {
        #pragma unroll
        for (int r = 0; r < 32; ++r) {
            if ((r & h) == 0) {
                float a = w[r], bb = w[r + h];
                w[r] = a + bb;
                w[r + h] = a - bb;
            }
        }
    }

    // FHT bit 10: partner lane u^1 (quad_perm DPP)
    #pragma unroll
    for (int r = 0; r < 32; ++r) {
        const float o = __shfl_xor(w[r], 1, 64);
        w[r] = b ? (o - w[r]) : (w[r] + o);
    }

    // SV multiply + non-temporal f32 store: e = 1024*b + 32*r + j0
    const size_t obase = (size_t)tok * 2048;
    const int ebase = (b << 10) | j0;
    #pragma unroll
    for (int r = 0; r < 32; ++r) {
        const int e = ebase + (r << 5);
        __builtin_nontemporal_store(w[r] * SV[e], &out[obase + e]);
    }
}

// ---------- fallback (f32 gathers) — used if workspace too small -----------
__global__ __launch_bounds__(256, 4) void e8rht_kernel_f(
    const int* __restrict__ input_ids,
    const int* __restrict__ Qidxs,
    const int* __restrict__ Qidxs2,
    const float* __restrict__ codebook,
    const float* __restrict__ codebook2,
    const float* __restrict__ SV,
    const float* __restrict__ Wscale,
    const float* __restrict__ inv_resid,
    float* __restrict__ out)
{
    __shared__ __align__(16) float lds[WPB * 2048];
    const int wave = threadIdx.x >> 6;
    const int lane = threadIdx.x & 63;
    const int tok  = blockIdx.x * WPB + wave;

    const float ws  = Wscale[0];
    const float ws2 = ws * inv_resid[0];
    const int tid = input_ids[tok];

    const int4 q1 = *(const int4*)(Qidxs  + (size_t)tid * 256 + lane * 4);
    const int4 q2 = *(const int4*)(Qidxs2 + (size_t)tid * 256 + lane * 4);

    float v[32];
    {
        const int i1[4] = { q1.x & 0xFFFF, q1.y & 0xFFFF, q1.z & 0xFFFF, q1.w & 0xFFFF };
        const int i2[4] = { q2.x & 0xFFFF, q2.y & 0xFFFF, q2.z & 0xFFFF, q2.w & 0xFFFF };
        #pragma unroll
        for (int c = 0; c < 4; ++c) {
            const float4* r1 = (const float4*)(codebook  + (size_t)i1[c] * 8);
            const float4* r2 = (const float4*)(codebook2 + (size_t)i2[c] * 8);
            const float4 a0 = r1[0], a1 = r1[1];
            const float4 b0 = r2[0], b1 = r2[1];
            v[8*c+0]=a0.x*ws+b0.x*ws2; v[8*c+1]=a0.y*ws+b0.y*ws2;
            v[8*c+2]=a0.z*ws+b0.z*ws2; v[8*c+3]=a0.w*ws+b0.w*ws2;
            v[8*c+4]=a1.x*ws+b1.x*ws2; v[8*c+5]=a1.y*ws+b1.y*ws2;
            v[8*c+6]=a1.z*ws+b1.z*ws2; v[8*c+7]=a1.w*ws+b1.w*ws2;
        }
    }
    #pragma unroll
    for (int h = 1; h < 32; h <<= 1)
        #pragma unroll
        for (int r = 0; r < 32; ++r)
            if ((r & h) == 0) { float a=v[r],b=v[r+h]; v[r]=a+b; v[r+h]=a-b; }

    float* L = lds + wave * 2048;
    {
        const int t4 = lane >> 2, tl = lane & 3;
        #pragma unroll
        for (int j = 0; j < 32; ++j)
            L[(j << 6) + (((t4 ^ (j & 15)) << 2) | tl)] = v[j];
    }
    __syncthreads();
    const int j0 = lane >> 1;
    const int b  = lane & 1;
    float w[32];
    {
        const float4* Lr = (const float4*)(L + (j0 << 6));
        #pragma unroll
        for (int c = 0; c < 8; ++c) {
            const float4 f = Lr[((b << 3) + c) ^ (j0 & 15)];
            w[4*c+0]=f.x; w[4*c+1]=f.y; w[4*c+2]=f.z; w[4*c+3]=f.w;
        }
    }
    #pragma unroll
    for (int h = 1; h < 32; h <<= 1)
        #pragma unroll
        for (int r = 0; r < 32; ++r)
            if ((r & h) == 0) { float a=w[r],bb=w[r+h]; w[r]=a+bb; w[r+h]=a-bb; }
    #pragma unroll
    for (int r = 0; r < 32; ++r) {
        const float o = __shfl_xor(w[r], 1, 64);
        w[r] = b ? (o - w[r]) : (w[r] + o);
    }
    const size_t obase = (size_t)tok * 2048;
    const int ebase = (b << 10) | j0;
    #pragma unroll
    for (int r = 0; r < 32; ++r) {
        const int e = ebase + (r << 5);
        out[obase + e] = w[r] * SV[e];
    }
}

extern "C" void kernel_launch(void* const* d_in, const int* in_sizes, int n_in,
                              void* d_out, int out_size, void* d_ws, size_t ws_size,
                              hipStream_t stream) {
    const int* input_ids   = (const int*)d_in[0];
    const int* Qidxs       = (const int*)d_in[1];
    const int* Qidxs2      = (const int*)d_in[2];
    const float* codebook  = (const float*)d_in[3];
    const float* codebook2 = (const float*)d_in[4];
    const float* SV        = (const float*)d_in[5];
    const float* wscale    = (const float*)d_in[6];
    const float* irs       = (const float*)d_in[7];
    float* out             = (float*)d_out;

    const int n_tok = in_sizes[0];          // 16384
    const int grid  = n_tok / WPB;          // 4096 blocks

    const size_t cb_h_bytes = (size_t)65536 * 8 * 2;   // 1 MB per codebook
    if (ws_size >= 2 * cb_h_bytes) {
        unsigned int* cb1h = (unsigned int*)d_ws;
        unsigned int* cb2h = (unsigned int*)((char*)d_ws + cb_h_bytes);
        cvt_kernel<<<512, 256, 0, stream>>>(codebook, codebook2, cb1h, cb2h);
        e8rht_kernel_h<<<grid, 256, 0, stream>>>(input_ids, Qidxs, Qidxs2,
                                                 cb1h, cb2h, SV, wscale, irs, out);
    } else {
        e8rht_kernel_f<<<grid, 256, 0, stream>>>(input_ids, Qidxs, Qidxs2,
                                                 codebook, codebook2, SV,
                                                 wscale, irs, out);
    }
}

// Round 8
// 315.623 us; speedup vs baseline: 1.1056x; 1.1052x over previous
//
#include <hip/hip_runtime.h>
#include <hip/hip_fp16.h>

constexpr int WPB = 4;   // waves (=tokens) per block

typedef int   v4i __attribute__((ext_vector_type(4)));
typedef unsigned int v4u __attribute__((ext_vector_type(4)));

// ---------- pre-pass: f32 codebooks -> fp16 (lossless, data was fp16) ------
__global__ __launch_bounds__(256) void cvt_kernel(
    const float* __restrict__ cb1, const float* __restrict__ cb2,
    unsigned int* __restrict__ o1, unsigned int* __restrict__ o2)
{
    const int r = blockIdx.x * 256 + threadIdx.x;        // 0..131071
    const float* src = (r < 65536) ? (cb1 + (size_t)r * 8)
                                   : (cb2 + (size_t)(r - 65536) * 8);
    unsigned int* dst = (r < 65536) ? (o1 + (size_t)r * 4)
                                    : (o2 + (size_t)(r - 65536) * 4);
    const float4 a = ((const float4*)src)[0];
    const float4 b = ((const float4*)src)[1];
    __half2 h0 = __floats2half2_rn(a.x, a.y);
    __half2 h1 = __floats2half2_rn(a.z, a.w);
    __half2 h2 = __floats2half2_rn(b.x, b.y);
    __half2 h3 = __floats2half2_rn(b.z, b.w);
    v4u o;
    o.x = *(unsigned int*)&h0; o.y = *(unsigned int*)&h1;
    o.z = *(unsigned int*)&h2; o.w = *(unsigned int*)&h3;
    *(v4u*)dst = o;
}

// 16 B gather that BYPASSES L1 (sc0 = legacy glc: return data from L2, no
// L1 tag allocation / line fill) but allocates NORMALLY in L2 — round 7's
// `nt` destroyed codebook L2 residency (FETCH 24.9->63.4 MB); sc0-only is
// the clean L1-fill-bypass test. NOTE: asm loads are invisible to the
// compiler's vmcnt tracking — caller must s_waitcnt vmcnt(0) before use.
__device__ __forceinline__ v4u gload16_sc0(const unsigned int* p) {
    v4u r;
    asm volatile("global_load_dwordx4 %0, %1, off sc0"
                 : "=v"(r) : "v"(p) : "memory");
    return r;
}

// ---------- main kernel (fp16 codebook gathers, L1-bypass) -----------------
__global__ __launch_bounds__(256, 4) void e8rht_kernel_h(
    const int* __restrict__ input_ids,
    const int* __restrict__ Qidxs,
    const int* __restrict__ Qidxs2,
    const unsigned int* __restrict__ cb1h,   // fp16 pairs: row = 4 uints (16 B)
    const unsigned int* __restrict__ cb2h,
    const float* __restrict__ SV,
    const float* __restrict__ Wscale,
    const float* __restrict__ inv_resid,
    float* __restrict__ out)
{
    __shared__ __align__(16) float lds[WPB * 2048];
    const int wave = threadIdx.x >> 6;
    const int lane = threadIdx.x & 63;
    const int tok  = blockIdx.x * WPB + wave;

    const float ws  = Wscale[0];
    const float ws2 = ws * inv_resid[0];
    const int tid = input_ids[tok];

    // index rows: streamed once, non-temporal is correct here (keep L2 for
    // the codebooks)
    const v4i q1 = __builtin_nontemporal_load((const v4i*)(Qidxs  + (size_t)tid * 256 + lane * 4));
    const v4i q2 = __builtin_nontemporal_load((const v4i*)(Qidxs2 + (size_t)tid * 256 + lane * 4));

    float v[32];
    {
        const int i1[4] = { q1.x & 0xFFFF, q1.y & 0xFFFF, q1.z & 0xFFFF, q1.w & 0xFFFF };
        const int i2[4] = { q2.x & 0xFFFF, q2.y & 0xFFFF, q2.z & 0xFFFF, q2.w & 0xFFFF };

        // All 8 gathers issued back-to-back (volatile asm preserves order),
        // then one drain. The sched_barrier stops the compiler hoisting
        // converts above the waitcnt (asm loads invisible to its tracking).
        v4u a0 = gload16_sc0(cb1h + (size_t)i1[0] * 4);
        v4u a1 = gload16_sc0(cb1h + (size_t)i1[1] * 4);
        v4u a2 = gload16_sc0(cb1h + (size_t)i1[2] * 4);
        v4u a3 = gload16_sc0(cb1h + (size_t)i1[3] * 4);
        v4u b0 = gload16_sc0(cb2h + (size_t)i2[0] * 4);
        v4u b1 = gload16_sc0(cb2h + (size_t)i2[1] * 4);
        v4u b2 = gload16_sc0(cb2h + (size_t)i2[2] * 4);
        v4u b3 = gload16_sc0(cb2h + (size_t)i2[3] * 4);
        asm volatile("s_waitcnt vmcnt(0)" ::: "memory");
        __builtin_amdgcn_sched_barrier(0);

        const v4u ga[4] = { a0, a1, a2, a3 };
        const v4u gb[4] = { b0, b1, b2, b3 };
        #pragma unroll
        for (int c = 0; c < 4; ++c) {
            const unsigned int au[4] = { ga[c].x, ga[c].y, ga[c].z, ga[c].w };
            const unsigned int bu[4] = { gb[c].x, gb[c].y, gb[c].z, gb[c].w };
            #pragma unroll
            for (int p = 0; p < 4; ++p) {
                const float2 fa = __half22float2(*(const __half2*)&au[p]);
                const float2 fb = __half22float2(*(const __half2*)&bu[p]);
                v[8*c + 2*p]     = fa.x * ws + fb.x * ws2;
                v[8*c + 2*p + 1] = fa.y * ws + fb.y * ws2;
            }
        }
    }

    // FHT bits 0..4 (within-thread)
    #pragma unroll
    for (int h = 1; h < 32; h <<= 1) {
        #pragma unroll
        for (int r = 0; r < 32; ++r) {
            if ((r & h) == 0) {
                float a = v[r], b = v[r + h];
                v[r] = a + b;
                v[r + h] = a - b;
            }
        }
    }

    // Transposed LDS write (wave-private region, wave-synchronous — no block
    // barrier needed). col' = ((t>>2) ^ (j&15))*4 + (t&3): 2 lanes/bank, free.
    float* L = lds + wave * 2048;
    {
        const int t4 = lane >> 2, tl = lane & 3;
        #pragma unroll
        for (int j = 0; j < 32; ++j) {
            const int col = (((t4 ^ (j & 15)) << 2) | tl);
            L[(j << 6) + col] = v[j];
        }
    }
    __builtin_amdgcn_wave_barrier();   // pin ordering; lgkmcnt inserted by compiler

    // Phase 2: lane u = 2*j0 + b reads row j0, cols t = 32b..32b+31.
    const int j0 = lane >> 1;
    const int b  = lane & 1;
    float w[32];
    {
        const float4* Lr = (const float4*)(L + (j0 << 6));
        #pragma unroll
        for (int c = 0; c < 8; ++c) {
            const int ch = ((b << 3) + c) ^ (j0 & 15);
            const float4 f = Lr[ch];
            w[4*c + 0] = f.x; w[4*c + 1] = f.y; w[4*c + 2] = f.z; w[4*c + 3] = f.w;
        }
    }

    // FHT bits 5..9 (within-thread)
    #pragma unroll
    for (int h = 1; h < 32; h <<= 1) {
        #pragma unroll
        for (int r = 0; r < 32; ++r) {
            if ((r & h) == 0) {
                float a = w[r], bb = w[r + h];
                w[r] = a + bb;
                w[r + h] = a - bb;
            }
        }
    }

    // FHT bit 10: partner lane u^1 (quad_perm DPP)
    #pragma unroll
    for (int r = 0; r < 32; ++r) {
        const float o = __shfl_xor(w[r], 1, 64);
        w[r] = b ? (o - w[r]) : (w[r] + o);
    }

    // SV multiply + non-temporal f32 store: e = 1024*b + 32*r + j0
    const size_t obase = (size_t)tok * 2048;
    const int ebase = (b << 10) | j0;
    #pragma unroll
    for (int r = 0; r < 32; ++r) {
        const int e = ebase + (r << 5);
        __builtin_nontemporal_store(w[r] * SV[e], &out[obase + e]);
    }
}

// ---------- fallback (f32 gathers) — used if workspace too small -----------
__global__ __launch_bounds__(256, 4) void e8rht_kernel_f(
    const int* __restrict__ input_ids,
    const int* __restrict__ Qidxs,
    const int* __restrict__ Qidxs2,
    const float* __restrict__ codebook,
    const float* __restrict__ codebook2,
    const float* __restrict__ SV,
    const float* __restrict__ Wscale,
    const float* __restrict__ inv_resid,
    float* __restrict__ out)
{
    __shared__ __align__(16) float lds[WPB * 2048];
    const int wave = threadIdx.x >> 6;
    const int lane = threadIdx.x & 63;
    const int tok  = blockIdx.x * WPB + wave;

    const float ws  = Wscale[0];
    const float ws2 = ws * inv_resid[0];
    const int tid = input_ids[tok];

    const int4 q1 = *(const int4*)(Qidxs  + (size_t)tid * 256 + lane * 4);
    const int4 q2 = *(const int4*)(Qidxs2 + (size_t)tid * 256 + lane * 4);

    float v[32];
    {
        const int i1[4] = { q1.x & 0xFFFF, q1.y & 0xFFFF, q1.z & 0xFFFF, q1.w & 0xFFFF };
        const int i2[4] = { q2.x & 0xFFFF, q2.y & 0xFFFF, q2.z & 0xFFFF, q2.w & 0xFFFF };
        #pragma unroll
        for (int c = 0; c < 4; ++c) {
            const float4* r1 = (const float4*)(codebook  + (size_t)i1[c] * 8);
            const float4* r2 = (const float4*)(codebook2 + (size_t)i2[c] * 8);
            const float4 a0 = r1[0], a1 = r1[1];
            const float4 b0 = r2[0], b1 = r2[1];
            v[8*c+0]=a0.x*ws+b0.x*ws2; v[8*c+1]=a0.y*ws+b0.y*ws2;
            v[8*c+2]=a0.z*ws+b0.z*ws2; v[8*c+3]=a0.w*ws+b0.w*ws2;
            v[8*c+4]=a1.x*ws+b1.x*ws2; v[8*c+5]=a1.y*ws+b1.y*ws2;
            v[8*c+6]=a1.z*ws+b1.z*ws2; v[8*c+7]=a1.w*ws+b1.w*ws2;
        }
    }
    #pragma unroll
    for (int h = 1; h < 32; h <<= 1)
        #pragma unroll
        for (int r = 0; r < 32; ++r)
            if ((r & h) == 0) { float a=v[r],b=v[r+h]; v[r]=a+b; v[r+h]=a-b; }

    float* L = lds + wave * 2048;
    {
        const int t4 = lane >> 2, tl = lane & 3;
        #pragma unroll
        for (int j = 0; j < 32; ++j)
            L[(j << 6) + (((t4 ^ (j & 15)) << 2) | tl)] = v[j];
    }
    __syncthreads();
    const int j0 = lane >> 1;
    const int b  = lane & 1;
    float w[32];
    {
        const float4* Lr = (const float4*)(L + (j0 << 6));
        #pragma unroll
        for (int c = 0; c < 8; ++c) {
            const float4 f = Lr[((b << 3) + c) ^ (j0 & 15)];
            w[4*c+0]=f.x; w[4*c+1]=f.y; w[4*c+2]=f.z; w[4*c+3]=f.w;
        }
    }
    #pragma unroll
    for (int h = 1; h < 32; h <<= 1)
        #pragma unroll
        for (int r = 0; r < 32; ++r)
            if ((r & h) == 0) { float a=w[r],bb=w[r+h]; w[r]=a+bb; w[r+h]=a-bb; }
    #pragma unroll
    for (int r = 0; r < 32; ++r) {
        const float o = __shfl_xor(w[r], 1, 64);
        w[r] = b ? (o - w[r]) : (w[r] + o);
    }
    const size_t obase = (size_t)tok * 2048;
    const int ebase = (b << 10) | j0;
    #pragma unroll
    for (int r = 0; r < 32; ++r) {
        const int e = ebase + (r << 5);
        out[obase + e] = w[r] * SV[e];
    }
}

extern "C" void kernel_launch(void* const* d_in, const int* in_sizes, int n_in,
                              void* d_out, int out_size, void* d_ws, size_t ws_size,
                              hipStream_t stream) {
    const int* input_ids   = (const int*)d_in[0];
    const int* Qidxs       = (const int*)d_in[1];
    const int* Qidxs2      = (const int*)d_in[2];
    const float* codebook  = (const float*)d_in[3];
    const float* codebook2 = (const float*)d_in[4];
    const float* SV        = (const float*)d_in[5];
    const float* wscale    = (const float*)d_in[6];
    const float* irs       = (const float*)d_in[7];
    float* out             = (float*)d_out;

    const int n_tok = in_sizes[0];          // 16384
    const int grid  = n_tok / WPB;          // 4096 blocks

    const size_t cb_h_bytes = (size_t)65536 * 8 * 2;   // 1 MB per codebook
    if (ws_size >= 2 * cb_h_bytes) {
        unsigned int* cb1h = (unsigned int*)d_ws;
        unsigned int* cb2h = (unsigned int*)((char*)d_ws + cb_h_bytes);
        cvt_kernel<<<512, 256, 0, stream>>>(codebook, codebook2, cb1h, cb2h);
        e8rht_kernel_h<<<grid, 256, 0, stream>>>(input_ids, Qidxs, Qidxs2,
                                                 cb1h, cb2h, SV, wscale, irs, out);
    } else {
        e8rht_kernel_f<<<grid, 256, 0, stream>>>(input_ids, Qidxs, Qidxs2,
                                                 codebook, codebook2, SV,
                                                 wscale, irs, out);
    }
}